// Round 1
// baseline (22634.752 us; speedup 1.0000x reference)
//
#include <hip/hip_runtime.h>

#define N_NODES 200000
#define N_EDGES 6400000
#define EMB 16
#define CONT 12
#define H 128
#define IN_DIM 60   // 3*EMB + CONT
#define NPB 32      // nodes per block for dense kernels (200000 % 32 == 0)
#define TPB 256

// ---------------------------------------------------------------------------
// K1: fused embedding gather + 2-layer input MLP
// h[node] = relu(relu(x @ W1 + b1) @ W2 + b2),  x = [m_emb|w_emb|t_emb|cont]
// ---------------------------------------------------------------------------
__global__ __launch_bounds__(TPB) void k_input_mlp(
    const int* __restrict__ midx, const int* __restrict__ widx,
    const int* __restrict__ tidx, const float* __restrict__ cont,
    const float* __restrict__ memb, const float* __restrict__ wemb,
    const float* __restrict__ temb,
    const float* __restrict__ W1, const float* __restrict__ b1,
    const float* __restrict__ W2, const float* __restrict__ b2,
    float* __restrict__ h)
{
    __shared__ float x_lds[NPB][IN_DIM];
    __shared__ float h0_lds[NPB][H];
    const int tid  = threadIdx.x;
    const int base = blockIdx.x * NPB;

    // Phase A: gather x into LDS
    for (int idx = tid; idx < NPB * IN_DIM; idx += TPB) {
        int n = idx / IN_DIM, k = idx % IN_DIM;
        int node = base + n;
        float v;
        if (k < 16)       v = memb[midx[node] * 16 + k];
        else if (k < 32)  v = wemb[widx[node] * 16 + (k - 16)];
        else if (k < 48)  v = temb[tidx[node] * 16 + (k - 32)];
        else              v = cont[(size_t)node * CONT + (k - 48)];
        x_lds[n][k] = v;
    }
    __syncthreads();

    const int col  = tid & 127;
    const int half = tid >> 7;   // wave-uniform (0 for tid<128, 1 otherwise)

    // Phase B: h0 = relu(x @ W1 + b1)
    float acc[16];
    #pragma unroll
    for (int i = 0; i < 16; i++) acc[i] = 0.f;
    for (int k = 0; k < IN_DIM; k++) {
        float w = W1[k * H + col];
        #pragma unroll
        for (int i = 0; i < 16; i++)
            acc[i] += x_lds[half * 16 + i][k] * w;
    }
    float bb = b1[col];
    #pragma unroll
    for (int i = 0; i < 16; i++)
        h0_lds[half * 16 + i][col] = fmaxf(acc[i] + bb, 0.f);
    __syncthreads();

    // Phase C: h = relu(h0 @ W2 + b2)
    #pragma unroll
    for (int i = 0; i < 16; i++) acc[i] = 0.f;
    for (int k = 0; k < H; k++) {
        float w = W2[k * H + col];
        #pragma unroll
        for (int i = 0; i < 16; i++)
            acc[i] += h0_lds[half * 16 + i][k] * w;
    }
    bb = b2[col];
    #pragma unroll
    for (int i = 0; i < 16; i++) {
        int node = base + half * 16 + i;
        h[(size_t)node * H + col] = fmaxf(acc[i] + bb, 0.f);
    }
}

// ---------------------------------------------------------------------------
// K2: SpMM scatter: neigh[row] += val * h[col]   (32 threads per edge, float4)
// ---------------------------------------------------------------------------
__global__ __launch_bounds__(TPB) void k_spmm_atomic(
    const int* __restrict__ erow, const int* __restrict__ ecol,
    const float* __restrict__ eval, const float* __restrict__ h,
    float* __restrict__ neigh)
{
    unsigned int gid = blockIdx.x * TPB + threadIdx.x;
    int e = (int)(gid >> 5);
    if (e >= N_EDGES) return;
    int c = ((int)gid & 31) * 4;

    int col = ecol[e];
    int row = erow[e];
    float v = eval[e];

    const float4 hv = *(const float4*)(h + (size_t)col * H + c);
    float* dst = neigh + (size_t)row * H + c;
    unsafeAtomicAdd(dst + 0, v * hv.x);
    unsafeAtomicAdd(dst + 1, v * hv.y);
    unsafeAtomicAdd(dst + 2, v * hv.z);
    unsafeAtomicAdd(dst + 3, v * hv.w);
}

// ---------------------------------------------------------------------------
// K3: dense layer update: h += relu(h@Ws + bs + neigh@Wn + bn)   (in place)
// ---------------------------------------------------------------------------
__global__ __launch_bounds__(TPB) void k_layer_dense(
    const float* __restrict__ neigh,
    const float* __restrict__ Wself, const float* __restrict__ bself,
    const float* __restrict__ Wneigh, const float* __restrict__ bneigh,
    float* __restrict__ h)
{
    __shared__ float h_lds[NPB][H];
    __shared__ float n_lds[NPB][H];
    const int tid  = threadIdx.x;
    const int base = blockIdx.x * NPB;

    for (int idx = tid; idx < NPB * H; idx += TPB) {
        int n = idx >> 7, c = idx & 127;
        h_lds[n][c] = h[(size_t)(base + n) * H + c];
        n_lds[n][c] = neigh[(size_t)(base + n) * H + c];
    }
    __syncthreads();

    const int col  = tid & 127;
    const int half = tid >> 7;

    float acc[16];
    #pragma unroll
    for (int i = 0; i < 16; i++) acc[i] = 0.f;
    for (int k = 0; k < H; k++) {
        float ws = Wself[k * H + col];
        float wn = Wneigh[k * H + col];
        #pragma unroll
        for (int i = 0; i < 16; i++)
            acc[i] += h_lds[half * 16 + i][k] * ws + n_lds[half * 16 + i][k] * wn;
    }
    float bb = bself[col] + bneigh[col];
    #pragma unroll
    for (int i = 0; i < 16; i++) {
        int n = half * 16 + i;
        float out = fmaxf(acc[i] + bb, 0.f);
        h[(size_t)(base + n) * H + col] = h_lds[n][col] + out;
    }
}

// ---------------------------------------------------------------------------
// K4: partial mean/max pool over nodes -> atomics into g[0..255]
// h >= 0 everywhere (post-ReLU residual chain), so int atomicMax is valid
// and zero-init is a correct identity for both sum and max.
// ---------------------------------------------------------------------------
__global__ __launch_bounds__(TPB) void k_reduce(
    const float* __restrict__ h, float* __restrict__ g)
{
    __shared__ float s_sum[TPB];
    __shared__ float s_max[TPB];
    const int tid = threadIdx.x;
    const int col = tid & 127;
    const int rg  = tid >> 7;

    float sum = 0.f, mx = 0.f;
    for (int row = blockIdx.x * 2 + rg; row < N_NODES; row += gridDim.x * 2) {
        float v = h[(size_t)row * H + col];
        sum += v;
        mx = fmaxf(mx, v);
    }
    s_sum[tid] = sum;
    s_max[tid] = mx;
    __syncthreads();
    if (tid < 128) {
        sum = s_sum[tid] + s_sum[tid + 128];
        mx  = fmaxf(s_max[tid], s_max[tid + 128]);
        unsafeAtomicAdd(&g[col], sum);
        atomicMax((int*)&g[128 + col], __float_as_int(mx));
    }
}

__global__ void k_finalize(float* __restrict__ g)
{
    int t = threadIdx.x;
    if (t < 128) g[t] *= (1.0f / (float)N_NODES);
}

// ---------------------------------------------------------------------------
extern "C" void kernel_launch(void* const* d_in, const int* in_sizes, int n_in,
                              void* d_out, int out_size, void* d_ws, size_t ws_size,
                              hipStream_t stream)
{
    const int*   midx  = (const int*)  d_in[0];
    const int*   widx  = (const int*)  d_in[1];
    const int*   tidx  = (const int*)  d_in[2];
    const float* cont  = (const float*)d_in[3];
    const int*   erow  = (const int*)  d_in[4];
    const int*   ecol  = (const int*)  d_in[5];
    const float* eval  = (const float*)d_in[6];
    const float* memb  = (const float*)d_in[7];
    const float* wemb  = (const float*)d_in[8];
    const float* temb  = (const float*)d_in[9];
    const float* W1    = (const float*)d_in[10];
    const float* b1    = (const float*)d_in[11];
    const float* W2    = (const float*)d_in[12];
    const float* b2    = (const float*)d_in[13];
    const float* Wself = (const float*)d_in[14];
    const float* bself = (const float*)d_in[15];
    const float* Wneigh= (const float*)d_in[16];
    const float* bneigh= (const float*)d_in[17];

    float* g     = (float*)d_out;        // [256]
    float* h     = g + 256;              // [N, H], lives directly in d_out
    float* neigh = (float*)d_ws;         // [N, H] scratch (102.4 MB)

    // zero the pooled-output accumulators (d_out is poisoned before each call)
    hipMemsetAsync(d_out, 0, 256 * sizeof(float), stream);

    k_input_mlp<<<N_NODES / NPB, TPB, 0, stream>>>(
        midx, widx, tidx, cont, memb, wemb, temb, W1, b1, W2, b2, h);

    for (int l = 0; l < 2; l++) {
        hipMemsetAsync(neigh, 0, (size_t)N_NODES * H * sizeof(float), stream);
        unsigned int nthreads = (unsigned int)N_EDGES * 32u;
        k_spmm_atomic<<<nthreads / TPB, TPB, 0, stream>>>(erow, ecol, eval, h, neigh);
        k_layer_dense<<<N_NODES / NPB, TPB, 0, stream>>>(
            neigh, Wself + (size_t)l * H * H, bself + (size_t)l * H,
            Wneigh + (size_t)l * H * H, bneigh + (size_t)l * H, h);
    }

    k_reduce<<<2048, TPB, 0, stream>>>(h, g);
    k_finalize<<<1, 128, 0, stream>>>(g);
}

// Round 2
// 2898.114 us; speedup vs baseline: 7.8102x; 7.8102x over previous
//
#include <hip/hip_runtime.h>

#define N_NODES 200000
#define N_EDGES 6400000
#define EMB 16
#define CONT 12
#define H 128
#define IN_DIM 60   // 3*EMB + CONT
#define NPB 32      // nodes per block for dense kernels (200000 % 32 == 0)
#define TPB 256
#define SCAN_CHUNK 256
#define N_SCAN_BLOCKS ((N_NODES + SCAN_CHUNK - 1) / SCAN_CHUNK)   // 782

// ---------------------------------------------------------------------------
// K1: fused embedding gather + 2-layer input MLP
// ---------------------------------------------------------------------------
__global__ __launch_bounds__(TPB) void k_input_mlp(
    const int* __restrict__ midx, const int* __restrict__ widx,
    const int* __restrict__ tidx, const float* __restrict__ cont,
    const float* __restrict__ memb, const float* __restrict__ wemb,
    const float* __restrict__ temb,
    const float* __restrict__ W1, const float* __restrict__ b1,
    const float* __restrict__ W2, const float* __restrict__ b2,
    float* __restrict__ h)
{
    __shared__ float x_lds[NPB][IN_DIM];
    __shared__ float h0_lds[NPB][H];
    const int tid  = threadIdx.x;
    const int base = blockIdx.x * NPB;

    for (int idx = tid; idx < NPB * IN_DIM; idx += TPB) {
        int n = idx / IN_DIM, k = idx % IN_DIM;
        int node = base + n;
        float v;
        if (k < 16)       v = memb[midx[node] * 16 + k];
        else if (k < 32)  v = wemb[widx[node] * 16 + (k - 16)];
        else if (k < 48)  v = temb[tidx[node] * 16 + (k - 32)];
        else              v = cont[(size_t)node * CONT + (k - 48)];
        x_lds[n][k] = v;
    }
    __syncthreads();

    const int col  = tid & 127;
    const int half = tid >> 7;

    float acc[16];
    #pragma unroll
    for (int i = 0; i < 16; i++) acc[i] = 0.f;
    for (int k = 0; k < IN_DIM; k++) {
        float w = W1[k * H + col];
        #pragma unroll
        for (int i = 0; i < 16; i++)
            acc[i] += x_lds[half * 16 + i][k] * w;
    }
    float bb = b1[col];
    #pragma unroll
    for (int i = 0; i < 16; i++)
        h0_lds[half * 16 + i][col] = fmaxf(acc[i] + bb, 0.f);
    __syncthreads();

    #pragma unroll
    for (int i = 0; i < 16; i++) acc[i] = 0.f;
    for (int k = 0; k < H; k++) {
        float w = W2[k * H + col];
        #pragma unroll
        for (int i = 0; i < 16; i++)
            acc[i] += h0_lds[half * 16 + i][k] * w;
    }
    bb = b2[col];
    #pragma unroll
    for (int i = 0; i < 16; i++) {
        int node = base + half * 16 + i;
        h[(size_t)node * H + col] = fmaxf(acc[i] + bb, 0.f);
    }
}

// ---------------------------------------------------------------------------
// CSR build: histogram -> exclusive scan (3 phase) -> scatter
// ---------------------------------------------------------------------------
__global__ __launch_bounds__(TPB) void k_histogram(
    const int* __restrict__ erow, int* __restrict__ row_cnt)
{
    int e = blockIdx.x * TPB + threadIdx.x;
    if (e < N_EDGES) atomicAdd(&row_cnt[erow[e]], 1);
}

__global__ __launch_bounds__(SCAN_CHUNK) void k_scan_block_sums(
    const int* __restrict__ row_cnt, int* __restrict__ block_sums)
{
    __shared__ int s[SCAN_CHUNK];
    int i = blockIdx.x * SCAN_CHUNK + threadIdx.x;
    s[threadIdx.x] = (i < N_NODES) ? row_cnt[i] : 0;
    __syncthreads();
    for (int off = SCAN_CHUNK / 2; off > 0; off >>= 1) {
        if (threadIdx.x < off) s[threadIdx.x] += s[threadIdx.x + off];
        __syncthreads();
    }
    if (threadIdx.x == 0) block_sums[blockIdx.x] = s[0];
}

__global__ void k_scan_tops(int* __restrict__ block_sums, int* __restrict__ row_ptr)
{
    // single thread: exclusive scan of N_SCAN_BLOCKS partials (in place)
    if (threadIdx.x == 0 && blockIdx.x == 0) {
        int run = 0;
        for (int b = 0; b < N_SCAN_BLOCKS; b++) {
            int v = block_sums[b];
            block_sums[b] = run;
            run += v;
        }
        row_ptr[N_NODES] = run;   // == N_EDGES
    }
}

__global__ __launch_bounds__(SCAN_CHUNK) void k_scan_final(
    const int* __restrict__ row_cnt, const int* __restrict__ block_sums,
    int* __restrict__ row_ptr, int* __restrict__ row_work)
{
    __shared__ int s[SCAN_CHUNK];
    int i = blockIdx.x * SCAN_CHUNK + threadIdx.x;
    int cnt = (i < N_NODES) ? row_cnt[i] : 0;
    s[threadIdx.x] = cnt;
    __syncthreads();
    // Hillis-Steele inclusive scan
    for (int off = 1; off < SCAN_CHUNK; off <<= 1) {
        int v = (threadIdx.x >= off) ? s[threadIdx.x - off] : 0;
        __syncthreads();
        s[threadIdx.x] += v;
        __syncthreads();
    }
    if (i < N_NODES) {
        int excl = block_sums[blockIdx.x] + s[threadIdx.x] - cnt;
        row_ptr[i]  = excl;
        row_work[i] = excl;
    }
}

__global__ __launch_bounds__(TPB) void k_scatter(
    const int* __restrict__ erow, const int* __restrict__ ecol,
    const float* __restrict__ eval, int* __restrict__ row_work,
    int2* __restrict__ csr)
{
    int e = blockIdx.x * TPB + threadIdx.x;
    if (e >= N_EDGES) return;
    int r = erow[e];
    int pos = atomicAdd(&row_work[r], 1);
    csr[pos] = make_int2(ecol[e], __float_as_int(eval[e]));
}

// ---------------------------------------------------------------------------
// K2': CSR SpMM — one wave per row, float2 accumulator per lane, no atomics
// ---------------------------------------------------------------------------
__global__ __launch_bounds__(TPB) void k_spmm_csr(
    const int* __restrict__ row_ptr, const int2* __restrict__ csr,
    const float* __restrict__ h, float* __restrict__ neigh)
{
    int wave = (int)((blockIdx.x * TPB + threadIdx.x) >> 6);
    if (wave >= N_NODES) return;
    int lane = threadIdx.x & 63;

    int start = row_ptr[wave];
    int end   = row_ptr[wave + 1];

    float ax = 0.f, ay = 0.f;
    int e = start;
    for (; e + 2 <= end; e += 2) {
        int2 cv0 = csr[e];
        int2 cv1 = csr[e + 1];
        const float2 h0 = *((const float2*)(h + (size_t)cv0.x * H) + lane);
        const float2 h1 = *((const float2*)(h + (size_t)cv1.x * H) + lane);
        float v0 = __int_as_float(cv0.y);
        float v1 = __int_as_float(cv1.y);
        ax += v0 * h0.x + v1 * h1.x;
        ay += v0 * h0.y + v1 * h1.y;
    }
    if (e < end) {
        int2 cv = csr[e];
        const float2 hv = *((const float2*)(h + (size_t)cv.x * H) + lane);
        float v = __int_as_float(cv.y);
        ax += v * hv.x;
        ay += v * hv.y;
    }
    *((float2*)(neigh + (size_t)wave * H) + lane) = make_float2(ax, ay);
}

// ---------------------------------------------------------------------------
// K2 (fallback): atomic SpMM, used only if ws_size is too small for CSR
// ---------------------------------------------------------------------------
__global__ __launch_bounds__(TPB) void k_spmm_atomic(
    const int* __restrict__ erow, const int* __restrict__ ecol,
    const float* __restrict__ eval, const float* __restrict__ h,
    float* __restrict__ neigh)
{
    unsigned int gid = blockIdx.x * TPB + threadIdx.x;
    int e = (int)(gid >> 5);
    if (e >= N_EDGES) return;
    int c = ((int)gid & 31) * 4;
    int col = ecol[e];
    int row = erow[e];
    float v = eval[e];
    const float4 hv = *(const float4*)(h + (size_t)col * H + c);
    float* dst = neigh + (size_t)row * H + c;
    unsafeAtomicAdd(dst + 0, v * hv.x);
    unsafeAtomicAdd(dst + 1, v * hv.y);
    unsafeAtomicAdd(dst + 2, v * hv.z);
    unsafeAtomicAdd(dst + 3, v * hv.w);
}

// ---------------------------------------------------------------------------
// K3: dense layer update: h += relu(h@Ws + bs + neigh@Wn + bn)   (in place)
// ---------------------------------------------------------------------------
__global__ __launch_bounds__(TPB) void k_layer_dense(
    const float* __restrict__ neigh,
    const float* __restrict__ Wself, const float* __restrict__ bself,
    const float* __restrict__ Wneigh, const float* __restrict__ bneigh,
    float* __restrict__ h)
{
    __shared__ float h_lds[NPB][H];
    __shared__ float n_lds[NPB][H];
    const int tid  = threadIdx.x;
    const int base = blockIdx.x * NPB;

    for (int idx = tid; idx < NPB * H; idx += TPB) {
        int n = idx >> 7, c = idx & 127;
        h_lds[n][c] = h[(size_t)(base + n) * H + c];
        n_lds[n][c] = neigh[(size_t)(base + n) * H + c];
    }
    __syncthreads();

    const int col  = tid & 127;
    const int half = tid >> 7;

    float acc[16];
    #pragma unroll
    for (int i = 0; i < 16; i++) acc[i] = 0.f;
    for (int k = 0; k < H; k++) {
        float ws = Wself[k * H + col];
        float wn = Wneigh[k * H + col];
        #pragma unroll
        for (int i = 0; i < 16; i++)
            acc[i] += h_lds[half * 16 + i][k] * ws + n_lds[half * 16 + i][k] * wn;
    }
    float bb = bself[col] + bneigh[col];
    #pragma unroll
    for (int i = 0; i < 16; i++) {
        int n = half * 16 + i;
        float out = fmaxf(acc[i] + bb, 0.f);
        h[(size_t)(base + n) * H + col] = h_lds[n][col] + out;
    }
}

// ---------------------------------------------------------------------------
// K4: mean/max pool (h >= 0 so int atomicMax and zero identity are valid)
// ---------------------------------------------------------------------------
__global__ __launch_bounds__(TPB) void k_reduce(
    const float* __restrict__ h, float* __restrict__ g)
{
    __shared__ float s_sum[TPB];
    __shared__ float s_max[TPB];
    const int tid = threadIdx.x;
    const int col = tid & 127;
    const int rg  = tid >> 7;

    float sum = 0.f, mx = 0.f;
    for (int row = blockIdx.x * 2 + rg; row < N_NODES; row += gridDim.x * 2) {
        float v = h[(size_t)row * H + col];
        sum += v;
        mx = fmaxf(mx, v);
    }
    s_sum[tid] = sum;
    s_max[tid] = mx;
    __syncthreads();
    if (tid < 128) {
        sum = s_sum[tid] + s_sum[tid + 128];
        mx  = fmaxf(s_max[tid], s_max[tid + 128]);
        unsafeAtomicAdd(&g[col], sum);
        atomicMax((int*)&g[128 + col], __float_as_int(mx));
    }
}

__global__ void k_finalize(float* __restrict__ g)
{
    int t = threadIdx.x;
    if (t < 128) g[t] *= (1.0f / (float)N_NODES);
}

// ---------------------------------------------------------------------------
extern "C" void kernel_launch(void* const* d_in, const int* in_sizes, int n_in,
                              void* d_out, int out_size, void* d_ws, size_t ws_size,
                              hipStream_t stream)
{
    const int*   midx  = (const int*)  d_in[0];
    const int*   widx  = (const int*)  d_in[1];
    const int*   tidx  = (const int*)  d_in[2];
    const float* cont  = (const float*)d_in[3];
    const int*   erow  = (const int*)  d_in[4];
    const int*   ecol  = (const int*)  d_in[5];
    const float* eval  = (const float*)d_in[6];
    const float* memb  = (const float*)d_in[7];
    const float* wemb  = (const float*)d_in[8];
    const float* temb  = (const float*)d_in[9];
    const float* W1    = (const float*)d_in[10];
    const float* b1    = (const float*)d_in[11];
    const float* W2    = (const float*)d_in[12];
    const float* b2    = (const float*)d_in[13];
    const float* Wself = (const float*)d_in[14];
    const float* bself = (const float*)d_in[15];
    const float* Wneigh= (const float*)d_in[16];
    const float* bneigh= (const float*)d_in[17];

    float* g = (float*)d_out;   // [256]
    float* h = g + 256;         // [N, H] lives in d_out

    // ---- workspace layout (all sizes in elements) ----
    float* neigh      = (float*)d_ws;              // 25,600,000 floats
    int*   row_ptr    = (int*)(neigh + (size_t)N_NODES * H);  // N+2 (pad to even)
    int*   row_cnt    = row_ptr + (N_NODES + 2);   // N
    int*   row_work   = row_cnt + N_NODES;         // N
    int*   block_sums = row_work + N_NODES;        // 1024 (782 used)
    int2*  csr        = (int2*)(block_sums + 1024);// E int2, 8-B aligned
    const size_t ws_needed =
        (size_t)N_NODES * H * 4 + (size_t)(N_NODES + 2 + 2 * N_NODES + 1024) * 4
        + (size_t)N_EDGES * 8;

    hipMemsetAsync(d_out, 0, 256 * sizeof(float), stream);

    k_input_mlp<<<N_NODES / NPB, TPB, 0, stream>>>(
        midx, widx, tidx, cont, memb, wemb, temb, W1, b1, W2, b2, h);

    const bool use_csr = (ws_size >= ws_needed);

    if (use_csr) {
        // ---- build CSR once; reused by both layers ----
        hipMemsetAsync(row_cnt, 0, N_NODES * sizeof(int), stream);
        k_histogram<<<(N_EDGES + TPB - 1) / TPB, TPB, 0, stream>>>(erow, row_cnt);
        k_scan_block_sums<<<N_SCAN_BLOCKS, SCAN_CHUNK, 0, stream>>>(row_cnt, block_sums);
        k_scan_tops<<<1, 64, 0, stream>>>(block_sums, row_ptr);
        k_scan_final<<<N_SCAN_BLOCKS, SCAN_CHUNK, 0, stream>>>(
            row_cnt, block_sums, row_ptr, row_work);
        k_scatter<<<(N_EDGES + TPB - 1) / TPB, TPB, 0, stream>>>(
            erow, ecol, eval, row_work, csr);

        for (int l = 0; l < 2; l++) {
            k_spmm_csr<<<(N_NODES * 64) / TPB, TPB, 0, stream>>>(row_ptr, csr, h, neigh);
            k_layer_dense<<<N_NODES / NPB, TPB, 0, stream>>>(
                neigh, Wself + (size_t)l * H * H, bself + (size_t)l * H,
                Wneigh + (size_t)l * H * H, bneigh + (size_t)l * H, h);
        }
    } else {
        for (int l = 0; l < 2; l++) {
            hipMemsetAsync(neigh, 0, (size_t)N_NODES * H * sizeof(float), stream);
            unsigned int nthreads = (unsigned int)N_EDGES * 32u;
            k_spmm_atomic<<<nthreads / TPB, TPB, 0, stream>>>(erow, ecol, eval, h, neigh);
            k_layer_dense<<<N_NODES / NPB, TPB, 0, stream>>>(
                neigh, Wself + (size_t)l * H * H, bself + (size_t)l * H,
                Wneigh + (size_t)l * H * H, bneigh + (size_t)l * H, h);
        }
    }

    k_reduce<<<2048, TPB, 0, stream>>>(h, g);
    k_finalize<<<1, 128, 0, stream>>>(g);
}

// Round 3
// 2585.511 us; speedup vs baseline: 8.7545x; 1.1209x over previous
//
#include <hip/hip_runtime.h>

#define N_NODES 200000
#define N_EDGES 6400000
#define EMB 16
#define CONT 12
#define H 128
#define IN_DIM 60   // 3*EMB + CONT
#define NPB 32      // nodes per block for dense kernels (200000 % 32 == 0)
#define TPB 256
#define SCAN_CHUNK 256
#define N_SCAN_BLOCKS ((N_NODES + SCAN_CHUNK - 1) / SCAN_CHUNK)   // 782

// bf16 round-to-nearest-even pack helper (h >= 0, finite; no NaN concern)
__device__ __forceinline__ unsigned bf_rne(float f) {
    unsigned u = __float_as_uint(f);
    return (u + 0x7FFFu + ((u >> 16) & 1u)) >> 16;
}

// ---------------------------------------------------------------------------
// K1: fused embedding gather + 2-layer input MLP
// ---------------------------------------------------------------------------
__global__ __launch_bounds__(TPB) void k_input_mlp(
    const int* __restrict__ midx, const int* __restrict__ widx,
    const int* __restrict__ tidx, const float* __restrict__ cont,
    const float* __restrict__ memb, const float* __restrict__ wemb,
    const float* __restrict__ temb,
    const float* __restrict__ W1, const float* __restrict__ b1,
    const float* __restrict__ W2, const float* __restrict__ b2,
    float* __restrict__ h)
{
    __shared__ float x_lds[NPB][IN_DIM];
    __shared__ float h0_lds[NPB][H];
    const int tid  = threadIdx.x;
    const int base = blockIdx.x * NPB;

    for (int idx = tid; idx < NPB * IN_DIM; idx += TPB) {
        int n = idx / IN_DIM, k = idx % IN_DIM;
        int node = base + n;
        float v;
        if (k < 16)       v = memb[midx[node] * 16 + k];
        else if (k < 32)  v = wemb[widx[node] * 16 + (k - 16)];
        else if (k < 48)  v = temb[tidx[node] * 16 + (k - 32)];
        else              v = cont[(size_t)node * CONT + (k - 48)];
        x_lds[n][k] = v;
    }
    __syncthreads();

    const int col  = tid & 127;
    const int half = tid >> 7;

    float acc[16];
    #pragma unroll
    for (int i = 0; i < 16; i++) acc[i] = 0.f;
    for (int k = 0; k < IN_DIM; k++) {
        float w = W1[k * H + col];
        #pragma unroll
        for (int i = 0; i < 16; i++)
            acc[i] += x_lds[half * 16 + i][k] * w;
    }
    float bb = b1[col];
    #pragma unroll
    for (int i = 0; i < 16; i++)
        h0_lds[half * 16 + i][col] = fmaxf(acc[i] + bb, 0.f);
    __syncthreads();

    #pragma unroll
    for (int i = 0; i < 16; i++) acc[i] = 0.f;
    for (int k = 0; k < H; k++) {
        float w = W2[k * H + col];
        #pragma unroll
        for (int i = 0; i < 16; i++)
            acc[i] += h0_lds[half * 16 + i][k] * w;
    }
    bb = b2[col];
    #pragma unroll
    for (int i = 0; i < 16; i++) {
        int node = base + half * 16 + i;
        h[(size_t)node * H + col] = fmaxf(acc[i] + bb, 0.f);
    }
}

// ---------------------------------------------------------------------------
// K_pack: h (fp32) -> hb (bf16x2 packed in u32), one u32 per float2
// ---------------------------------------------------------------------------
__global__ __launch_bounds__(TPB) void k_pack(
    const float* __restrict__ h, unsigned* __restrict__ hb)
{
    int i = blockIdx.x * TPB + threadIdx.x;   // over N_NODES*64
    if (i >= N_NODES * 64) return;
    float2 v = ((const float2*)h)[i];
    hb[i] = bf_rne(v.x) | (bf_rne(v.y) << 16);
}

// ---------------------------------------------------------------------------
// CSR build: histogram -> exclusive scan -> scatter (NT stores)
// ---------------------------------------------------------------------------
__global__ __launch_bounds__(TPB) void k_histogram(
    const int* __restrict__ erow, int* __restrict__ row_cnt)
{
    int e = blockIdx.x * TPB + threadIdx.x;
    if (e < N_EDGES) atomicAdd(&row_cnt[erow[e]], 1);
}

__global__ __launch_bounds__(SCAN_CHUNK) void k_scan_block_sums(
    const int* __restrict__ row_cnt, int* __restrict__ block_sums)
{
    __shared__ int s[SCAN_CHUNK];
    int i = blockIdx.x * SCAN_CHUNK + threadIdx.x;
    s[threadIdx.x] = (i < N_NODES) ? row_cnt[i] : 0;
    __syncthreads();
    for (int off = SCAN_CHUNK / 2; off > 0; off >>= 1) {
        if (threadIdx.x < off) s[threadIdx.x] += s[threadIdx.x + off];
        __syncthreads();
    }
    if (threadIdx.x == 0) block_sums[blockIdx.x] = s[0];
}

// parallel single-block exclusive scan of the 782 block sums
__global__ __launch_bounds__(1024) void k_scan_tops(
    int* __restrict__ block_sums, int* __restrict__ row_ptr)
{
    __shared__ int s[1024];
    int t = threadIdx.x;
    int v = (t < N_SCAN_BLOCKS) ? block_sums[t] : 0;
    s[t] = v;
    __syncthreads();
    for (int off = 1; off < 1024; off <<= 1) {
        int u = (t >= off) ? s[t - off] : 0;
        __syncthreads();
        s[t] += u;
        __syncthreads();
    }
    if (t < N_SCAN_BLOCKS) block_sums[t] = s[t] - v;   // exclusive
    if (t == 0) row_ptr[N_NODES] = s[1023];            // total == N_EDGES
}

__global__ __launch_bounds__(SCAN_CHUNK) void k_scan_final(
    const int* __restrict__ row_cnt, const int* __restrict__ block_sums,
    int* __restrict__ row_ptr, int* __restrict__ row_work)
{
    __shared__ int s[SCAN_CHUNK];
    int i = blockIdx.x * SCAN_CHUNK + threadIdx.x;
    int cnt = (i < N_NODES) ? row_cnt[i] : 0;
    s[threadIdx.x] = cnt;
    __syncthreads();
    for (int off = 1; off < SCAN_CHUNK; off <<= 1) {
        int v = (threadIdx.x >= off) ? s[threadIdx.x - off] : 0;
        __syncthreads();
        s[threadIdx.x] += v;
        __syncthreads();
    }
    if (i < N_NODES) {
        int excl = block_sums[blockIdx.x] + s[threadIdx.x] - cnt;
        row_ptr[i]  = excl;
        row_work[i] = excl;
    }
}

__global__ __launch_bounds__(TPB) void k_scatter(
    const int* __restrict__ erow, const int* __restrict__ ecol,
    const float* __restrict__ eval, int* __restrict__ row_work,
    long long* __restrict__ csr)
{
    int e = blockIdx.x * TPB + threadIdx.x;
    if (e >= N_EDGES) return;
    int r = erow[e];
    int pos = atomicAdd(&row_work[r], 1);
    // int2{col, valbits} as one 8-B non-temporal store (streams past L2)
    unsigned long long packed =
        (unsigned long long)(unsigned)ecol[e] |
        ((unsigned long long)(unsigned)__float_as_int(eval[e]) << 32);
    __builtin_nontemporal_store((long long)packed, &csr[pos]);
}

// ---------------------------------------------------------------------------
// K2': CSR SpMM — one wave per row, bf16 gather, fp32 accumulate
// ---------------------------------------------------------------------------
__global__ __launch_bounds__(TPB) void k_spmm_csr_bf16(
    const int* __restrict__ row_ptr, const int2* __restrict__ csr,
    const unsigned* __restrict__ hb, float* __restrict__ neigh)
{
    int wave = (int)((blockIdx.x * TPB + threadIdx.x) >> 6);
    if (wave >= N_NODES) return;
    int lane = threadIdx.x & 63;

    int start = row_ptr[wave];
    int end   = row_ptr[wave + 1];

    float ax = 0.f, ay = 0.f;
    int e = start;
    for (; e + 4 <= end; e += 4) {
        int2 c0 = csr[e + 0];
        int2 c1 = csr[e + 1];
        int2 c2 = csr[e + 2];
        int2 c3 = csr[e + 3];
        unsigned g0 = hb[c0.x * 64 + lane];
        unsigned g1 = hb[c1.x * 64 + lane];
        unsigned g2 = hb[c2.x * 64 + lane];
        unsigned g3 = hb[c3.x * 64 + lane];
        float v0 = __int_as_float(c0.y), v1 = __int_as_float(c1.y);
        float v2 = __int_as_float(c2.y), v3 = __int_as_float(c3.y);
        ax += v0 * __uint_as_float(g0 << 16) + v1 * __uint_as_float(g1 << 16)
            + v2 * __uint_as_float(g2 << 16) + v3 * __uint_as_float(g3 << 16);
        ay += v0 * __uint_as_float(g0 & 0xFFFF0000u) + v1 * __uint_as_float(g1 & 0xFFFF0000u)
            + v2 * __uint_as_float(g2 & 0xFFFF0000u) + v3 * __uint_as_float(g3 & 0xFFFF0000u);
    }
    for (; e < end; e++) {
        int2 c = csr[e];
        unsigned g = hb[c.x * 64 + lane];
        float v = __int_as_float(c.y);
        ax += v * __uint_as_float(g << 16);
        ay += v * __uint_as_float(g & 0xFFFF0000u);
    }
    *((float2*)(neigh + (size_t)wave * H) + lane) = make_float2(ax, ay);
}

// fp32-gather variant (fallback when ws too small for hb)
__global__ __launch_bounds__(TPB) void k_spmm_csr_f32(
    const int* __restrict__ row_ptr, const int2* __restrict__ csr,
    const float* __restrict__ h, float* __restrict__ neigh)
{
    int wave = (int)((blockIdx.x * TPB + threadIdx.x) >> 6);
    if (wave >= N_NODES) return;
    int lane = threadIdx.x & 63;
    int start = row_ptr[wave];
    int end   = row_ptr[wave + 1];
    float ax = 0.f, ay = 0.f;
    int e = start;
    for (; e + 2 <= end; e += 2) {
        int2 cv0 = csr[e];
        int2 cv1 = csr[e + 1];
        const float2 h0 = *((const float2*)(h + (size_t)cv0.x * H) + lane);
        const float2 h1 = *((const float2*)(h + (size_t)cv1.x * H) + lane);
        float v0 = __int_as_float(cv0.y);
        float v1 = __int_as_float(cv1.y);
        ax += v0 * h0.x + v1 * h1.x;
        ay += v0 * h0.y + v1 * h1.y;
    }
    if (e < end) {
        int2 cv = csr[e];
        const float2 hv = *((const float2*)(h + (size_t)cv.x * H) + lane);
        float v = __int_as_float(cv.y);
        ax += v * hv.x;
        ay += v * hv.y;
    }
    *((float2*)(neigh + (size_t)wave * H) + lane) = make_float2(ax, ay);
}

// K2 (fallback): atomic SpMM if ws too small for any CSR
__global__ __launch_bounds__(TPB) void k_spmm_atomic(
    const int* __restrict__ erow, const int* __restrict__ ecol,
    const float* __restrict__ eval, const float* __restrict__ h,
    float* __restrict__ neigh)
{
    unsigned int gid = blockIdx.x * TPB + threadIdx.x;
    int e = (int)(gid >> 5);
    if (e >= N_EDGES) return;
    int c = ((int)gid & 31) * 4;
    int col = ecol[e];
    int row = erow[e];
    float v = eval[e];
    const float4 hv = *(const float4*)(h + (size_t)col * H + c);
    float* dst = neigh + (size_t)row * H + c;
    unsafeAtomicAdd(dst + 0, v * hv.x);
    unsafeAtomicAdd(dst + 1, v * hv.y);
    unsafeAtomicAdd(dst + 2, v * hv.z);
    unsafeAtomicAdd(dst + 3, v * hv.w);
}

// ---------------------------------------------------------------------------
// K3: dense layer update: h += relu(h@Ws + bs + neigh@Wn + bn)   (in place)
// ---------------------------------------------------------------------------
__global__ __launch_bounds__(TPB) void k_layer_dense(
    const float* __restrict__ neigh,
    const float* __restrict__ Wself, const float* __restrict__ bself,
    const float* __restrict__ Wneigh, const float* __restrict__ bneigh,
    float* __restrict__ h)
{
    __shared__ float h_lds[NPB][H];
    __shared__ float n_lds[NPB][H];
    const int tid  = threadIdx.x;
    const int base = blockIdx.x * NPB;

    for (int idx = tid; idx < NPB * H; idx += TPB) {
        int n = idx >> 7, c = idx & 127;
        h_lds[n][c] = h[(size_t)(base + n) * H + c];
        n_lds[n][c] = neigh[(size_t)(base + n) * H + c];
    }
    __syncthreads();

    const int col  = tid & 127;
    const int half = tid >> 7;

    float acc[16];
    #pragma unroll
    for (int i = 0; i < 16; i++) acc[i] = 0.f;
    for (int k = 0; k < H; k++) {
        float ws = Wself[k * H + col];
        float wn = Wneigh[k * H + col];
        #pragma unroll
        for (int i = 0; i < 16; i++)
            acc[i] += h_lds[half * 16 + i][k] * ws + n_lds[half * 16 + i][k] * wn;
    }
    float bb = bself[col] + bneigh[col];
    #pragma unroll
    for (int i = 0; i < 16; i++) {
        int n = half * 16 + i;
        float out = fmaxf(acc[i] + bb, 0.f);
        h[(size_t)(base + n) * H + col] = h_lds[n][col] + out;
    }
}

// ---------------------------------------------------------------------------
// K4: mean/max pool (h >= 0 so int atomicMax and zero identity are valid)
// ---------------------------------------------------------------------------
__global__ __launch_bounds__(TPB) void k_reduce(
    const float* __restrict__ h, float* __restrict__ g)
{
    __shared__ float s_sum[TPB];
    __shared__ float s_max[TPB];
    const int tid = threadIdx.x;
    const int col = tid & 127;
    const int rg  = tid >> 7;

    float sum = 0.f, mx = 0.f;
    for (int row = blockIdx.x * 2 + rg; row < N_NODES; row += gridDim.x * 2) {
        float v = h[(size_t)row * H + col];
        sum += v;
        mx = fmaxf(mx, v);
    }
    s_sum[tid] = sum;
    s_max[tid] = mx;
    __syncthreads();
    if (tid < 128) {
        sum = s_sum[tid] + s_sum[tid + 128];
        mx  = fmaxf(s_max[tid], s_max[tid + 128]);
        unsafeAtomicAdd(&g[col], sum);
        atomicMax((int*)&g[128 + col], __float_as_int(mx));
    }
}

__global__ void k_finalize(float* __restrict__ g)
{
    int t = threadIdx.x;
    if (t < 128) g[t] *= (1.0f / (float)N_NODES);
}

// ---------------------------------------------------------------------------
extern "C" void kernel_launch(void* const* d_in, const int* in_sizes, int n_in,
                              void* d_out, int out_size, void* d_ws, size_t ws_size,
                              hipStream_t stream)
{
    const int*   midx  = (const int*)  d_in[0];
    const int*   widx  = (const int*)  d_in[1];
    const int*   tidx  = (const int*)  d_in[2];
    const float* cont  = (const float*)d_in[3];
    const int*   erow  = (const int*)  d_in[4];
    const int*   ecol  = (const int*)  d_in[5];
    const float* eval  = (const float*)d_in[6];
    const float* memb  = (const float*)d_in[7];
    const float* wemb  = (const float*)d_in[8];
    const float* temb  = (const float*)d_in[9];
    const float* W1    = (const float*)d_in[10];
    const float* b1    = (const float*)d_in[11];
    const float* W2    = (const float*)d_in[12];
    const float* b2    = (const float*)d_in[13];
    const float* Wself = (const float*)d_in[14];
    const float* bself = (const float*)d_in[15];
    const float* Wneigh= (const float*)d_in[16];
    const float* bneigh= (const float*)d_in[17];

    float* g = (float*)d_out;   // [256]
    float* h = g + 256;         // [N, H] lives in d_out

    // ---- workspace layout ----
    float*    neigh      = (float*)d_ws;                           // 102.4 MB
    unsigned* hb         = (unsigned*)(neigh + (size_t)N_NODES * H); // 51.2 MB
    int*      row_ptr    = (int*)(hb + (size_t)N_NODES * H / 2);
    int*      row_cnt    = row_ptr + (N_NODES + 2);
    int*      row_work   = row_cnt + N_NODES;
    int*      block_sums = row_work + N_NODES;
    long long* csr       = (long long*)(block_sums + 1024);        // 51.2 MB

    const size_t base_bytes = (size_t)N_NODES * H * 4
                            + (size_t)(3 * N_NODES + 2 + 1024) * 4
                            + (size_t)N_EDGES * 8;
    const size_t ws_full    = base_bytes + (size_t)N_NODES * H * 2;   // ~207 MB
    const bool use_csr  = (ws_size >= base_bytes);
    const bool use_bf16 = (ws_size >= ws_full);

    if (use_csr && !use_bf16) {
        // compact layout without hb (round-2 layout)
        row_ptr    = (int*)(neigh + (size_t)N_NODES * H);
        row_cnt    = row_ptr + (N_NODES + 2);
        row_work   = row_cnt + N_NODES;
        block_sums = row_work + N_NODES;
        csr        = (long long*)(block_sums + 1024);
    }

    hipMemsetAsync(d_out, 0, 256 * sizeof(float), stream);

    k_input_mlp<<<N_NODES / NPB, TPB, 0, stream>>>(
        midx, widx, tidx, cont, memb, wemb, temb, W1, b1, W2, b2, h);

    if (use_csr) {
        hipMemsetAsync(row_cnt, 0, N_NODES * sizeof(int), stream);
        k_histogram<<<(N_EDGES + TPB - 1) / TPB, TPB, 0, stream>>>(erow, row_cnt);
        k_scan_block_sums<<<N_SCAN_BLOCKS, SCAN_CHUNK, 0, stream>>>(row_cnt, block_sums);
        k_scan_tops<<<1, 1024, 0, stream>>>(block_sums, row_ptr);
        k_scan_final<<<N_SCAN_BLOCKS, SCAN_CHUNK, 0, stream>>>(
            row_cnt, block_sums, row_ptr, row_work);
        k_scatter<<<(N_EDGES + TPB - 1) / TPB, TPB, 0, stream>>>(
            erow, ecol, eval, row_work, csr);

        for (int l = 0; l < 2; l++) {
            if (use_bf16) {
                k_pack<<<(N_NODES * 64 + TPB - 1) / TPB, TPB, 0, stream>>>(h, hb);
                k_spmm_csr_bf16<<<(N_NODES * 64) / TPB, TPB, 0, stream>>>(
                    row_ptr, (const int2*)csr, hb, neigh);
            } else {
                k_spmm_csr_f32<<<(N_NODES * 64) / TPB, TPB, 0, stream>>>(
                    row_ptr, (const int2*)csr, h, neigh);
            }
            k_layer_dense<<<N_NODES / NPB, TPB, 0, stream>>>(
                neigh, Wself + (size_t)l * H * H, bself + (size_t)l * H,
                Wneigh + (size_t)l * H * H, bneigh + (size_t)l * H, h);
        }
    } else {
        for (int l = 0; l < 2; l++) {
            hipMemsetAsync(neigh, 0, (size_t)N_NODES * H * sizeof(float), stream);
            unsigned int nthreads = (unsigned int)N_EDGES * 32u;
            k_spmm_atomic<<<nthreads / TPB, TPB, 0, stream>>>(erow, ecol, eval, h, neigh);
            k_layer_dense<<<N_NODES / NPB, TPB, 0, stream>>>(
                neigh, Wself + (size_t)l * H * H, bself + (size_t)l * H,
                Wneigh + (size_t)l * H * H, bneigh + (size_t)l * H, h);
        }
    }

    k_reduce<<<2048, TPB, 0, stream>>>(h, g);
    k_finalize<<<1, 128, 0, stream>>>(g);
}

// Round 4
// 2341.647 us; speedup vs baseline: 9.6662x; 1.1041x over previous
//
#include <hip/hip_runtime.h>

#define N_NODES 200000
#define N_EDGES 6400000
#define EMB 16
#define CONT 12
#define H 128
#define IN_DIM 60   // 3*EMB + CONT
#define NPB 32      // nodes per block for dense kernels (200000 % 32 == 0)
#define TPB 256
#define SCAN_CHUNK 256
#define N_SCAN_BLOCKS ((N_NODES + SCAN_CHUNK - 1) / SCAN_CHUNK)   // 782

// bf16 round-to-nearest-even pack helper (h >= 0, finite; no NaN concern)
__device__ __forceinline__ unsigned bf_rne(float f) {
    unsigned u = __float_as_uint(f);
    return (u + 0x7FFFu + ((u >> 16) & 1u)) >> 16;
}

// ---------------------------------------------------------------------------
// K1: fused embedding gather + 2-layer input MLP + optional bf16 pack.
// 4x4 register blocking: thread = (r_grp = tid>>5) x (c_grp = tid&31),
// owns rows r0..r0+3, cols c0..c0+3. LDS reads are float4 over k with only
// 2 distinct addresses per wave (broadcast, conflict-free) -> FMA-bound.
// ---------------------------------------------------------------------------
__global__ __launch_bounds__(TPB) void k_input_mlp(
    const int* __restrict__ midx, const int* __restrict__ widx,
    const int* __restrict__ tidx, const float* __restrict__ cont,
    const float* __restrict__ memb, const float* __restrict__ wemb,
    const float* __restrict__ temb,
    const float* __restrict__ W1, const float* __restrict__ b1,
    const float* __restrict__ W2, const float* __restrict__ b2,
    float* __restrict__ h, unsigned* __restrict__ hb)
{
    __shared__ float x_lds[NPB][IN_DIM];   // 7.7 KB
    __shared__ float h0_lds[NPB][H];       // 16 KB
    const int tid  = threadIdx.x;
    const int base = blockIdx.x * NPB;

    // Phase A: gather x into LDS
    for (int idx = tid; idx < NPB * IN_DIM; idx += TPB) {
        int n = idx / IN_DIM, k = idx % IN_DIM;
        int node = base + n;
        float v;
        if (k < 16)       v = memb[midx[node] * 16 + k];
        else if (k < 32)  v = wemb[widx[node] * 16 + (k - 16)];
        else if (k < 48)  v = temb[tidx[node] * 16 + (k - 32)];
        else              v = cont[(size_t)node * CONT + (k - 48)];
        x_lds[n][k] = v;
    }
    __syncthreads();

    const int c0 = (tid & 31) * 4;
    const int r0 = (tid >> 5) * 4;

    // Phase B: h0 = relu(x @ W1 + b1)   (K = 60 = 15 * 4)
    float acc[4][4];
    #pragma unroll
    for (int i = 0; i < 4; i++)
        #pragma unroll
        for (int j = 0; j < 4; j++) acc[i][j] = 0.f;

    for (int k = 0; k < IN_DIM; k += 4) {
        float4 a[4];
        #pragma unroll
        for (int i = 0; i < 4; i++) a[i] = *(const float4*)&x_lds[r0 + i][k];
        #pragma unroll
        for (int kk = 0; kk < 4; kk++) {
            float4 w = *(const float4*)(W1 + (size_t)(k + kk) * H + c0);
            const float* wf = (const float*)&w;
            #pragma unroll
            for (int i = 0; i < 4; i++) {
                float av = ((const float*)&a[i])[kk];
                #pragma unroll
                for (int j = 0; j < 4; j++)
                    acc[i][j] += av * wf[j];
            }
        }
    }
    {
        float4 bv = *(const float4*)(b1 + c0);
        const float* bf = (const float*)&bv;
        #pragma unroll
        for (int i = 0; i < 4; i++)
            #pragma unroll
            for (int j = 0; j < 4; j++)
                h0_lds[r0 + i][c0 + j] = fmaxf(acc[i][j] + bf[j], 0.f);
    }
    __syncthreads();

    // Phase C: h = relu(h0 @ W2 + b2)   (K = 128)
    #pragma unroll
    for (int i = 0; i < 4; i++)
        #pragma unroll
        for (int j = 0; j < 4; j++) acc[i][j] = 0.f;

    for (int k = 0; k < H; k += 4) {
        float4 a[4];
        #pragma unroll
        for (int i = 0; i < 4; i++) a[i] = *(const float4*)&h0_lds[r0 + i][k];
        #pragma unroll
        for (int kk = 0; kk < 4; kk++) {
            float4 w = *(const float4*)(W2 + (size_t)(k + kk) * H + c0);
            const float* wf = (const float*)&w;
            #pragma unroll
            for (int i = 0; i < 4; i++) {
                float av = ((const float*)&a[i])[kk];
                #pragma unroll
                for (int j = 0; j < 4; j++)
                    acc[i][j] += av * wf[j];
            }
        }
    }
    {
        float4 bv = *(const float4*)(b2 + c0);
        const float* bf = (const float*)&bv;
        #pragma unroll
        for (int i = 0; i < 4; i++) {
            int node = base + r0 + i;
            float4 out;
            float* of = (float*)&out;
            #pragma unroll
            for (int j = 0; j < 4; j++)
                of[j] = fmaxf(acc[i][j] + bf[j], 0.f);
            *(float4*)(h + (size_t)node * H + c0) = out;
            if (hb) {
                uint2 p;
                p.x = bf_rne(of[0]) | (bf_rne(of[1]) << 16);
                p.y = bf_rne(of[2]) | (bf_rne(of[3]) << 16);
                *(uint2*)(hb + (size_t)node * 64 + (c0 >> 1)) = p;
            }
        }
    }
}

// ---------------------------------------------------------------------------
// CSR build: histogram -> exclusive scan -> scatter
// ---------------------------------------------------------------------------
__global__ __launch_bounds__(TPB) void k_histogram(
    const int* __restrict__ erow, int* __restrict__ row_cnt)
{
    int e = blockIdx.x * TPB + threadIdx.x;
    if (e < N_EDGES) atomicAdd(&row_cnt[erow[e]], 1);
}

__global__ __launch_bounds__(SCAN_CHUNK) void k_scan_block_sums(
    const int* __restrict__ row_cnt, int* __restrict__ block_sums)
{
    __shared__ int s[SCAN_CHUNK];
    int i = blockIdx.x * SCAN_CHUNK + threadIdx.x;
    s[threadIdx.x] = (i < N_NODES) ? row_cnt[i] : 0;
    __syncthreads();
    for (int off = SCAN_CHUNK / 2; off > 0; off >>= 1) {
        if (threadIdx.x < off) s[threadIdx.x] += s[threadIdx.x + off];
        __syncthreads();
    }
    if (threadIdx.x == 0) block_sums[blockIdx.x] = s[0];
}

// parallel single-block exclusive scan of the 782 block sums
__global__ __launch_bounds__(1024) void k_scan_tops(
    int* __restrict__ block_sums, int* __restrict__ row_ptr)
{
    __shared__ int s[1024];
    int t = threadIdx.x;
    int v = (t < N_SCAN_BLOCKS) ? block_sums[t] : 0;
    s[t] = v;
    __syncthreads();
    for (int off = 1; off < 1024; off <<= 1) {
        int u = (t >= off) ? s[t - off] : 0;
        __syncthreads();
        s[t] += u;
        __syncthreads();
    }
    if (t < N_SCAN_BLOCKS) block_sums[t] = s[t] - v;   // exclusive
    if (t == 0) row_ptr[N_NODES] = s[1023];            // total == N_EDGES
}

__global__ __launch_bounds__(SCAN_CHUNK) void k_scan_final(
    const int* __restrict__ row_cnt, const int* __restrict__ block_sums,
    int* __restrict__ row_ptr, int* __restrict__ row_work)
{
    __shared__ int s[SCAN_CHUNK];
    int i = blockIdx.x * SCAN_CHUNK + threadIdx.x;
    int cnt = (i < N_NODES) ? row_cnt[i] : 0;
    s[threadIdx.x] = cnt;
    __syncthreads();
    for (int off = 1; off < SCAN_CHUNK; off <<= 1) {
        int v = (threadIdx.x >= off) ? s[threadIdx.x - off] : 0;
        __syncthreads();
        s[threadIdx.x] += v;
        __syncthreads();
    }
    if (i < N_NODES) {
        int excl = block_sums[blockIdx.x] + s[threadIdx.x] - cnt;
        row_ptr[i]  = excl;
        row_work[i] = excl;
    }
}

__global__ __launch_bounds__(TPB) void k_scatter(
    const int* __restrict__ erow, const int* __restrict__ ecol,
    const float* __restrict__ eval, int* __restrict__ row_work,
    long long* __restrict__ csr)
{
    int e = blockIdx.x * TPB + threadIdx.x;
    if (e >= N_EDGES) return;
    int r = erow[e];
    int pos = atomicAdd(&row_work[r], 1);
    unsigned long long packed =
        (unsigned long long)(unsigned)ecol[e] |
        ((unsigned long long)(unsigned)__float_as_int(eval[e]) << 32);
    __builtin_nontemporal_store((long long)packed, &csr[pos]);
}

// ---------------------------------------------------------------------------
// K2': CSR SpMM — one wave per row, bf16 gather, fp32 accumulate
// ---------------------------------------------------------------------------
__global__ __launch_bounds__(TPB) void k_spmm_csr_bf16(
    const int* __restrict__ row_ptr, const int2* __restrict__ csr,
    const unsigned* __restrict__ hb, float* __restrict__ neigh)
{
    int wave = (int)((blockIdx.x * TPB + threadIdx.x) >> 6);
    if (wave >= N_NODES) return;
    int lane = threadIdx.x & 63;

    int start = row_ptr[wave];
    int end   = row_ptr[wave + 1];

    float ax = 0.f, ay = 0.f;
    int e = start;
    for (; e + 4 <= end; e += 4) {
        int2 c0 = csr[e + 0];
        int2 c1 = csr[e + 1];
        int2 c2 = csr[e + 2];
        int2 c3 = csr[e + 3];
        unsigned g0 = hb[c0.x * 64 + lane];
        unsigned g1 = hb[c1.x * 64 + lane];
        unsigned g2 = hb[c2.x * 64 + lane];
        unsigned g3 = hb[c3.x * 64 + lane];
        float v0 = __int_as_float(c0.y), v1 = __int_as_float(c1.y);
        float v2 = __int_as_float(c2.y), v3 = __int_as_float(c3.y);
        ax += v0 * __uint_as_float(g0 << 16) + v1 * __uint_as_float(g1 << 16)
            + v2 * __uint_as_float(g2 << 16) + v3 * __uint_as_float(g3 << 16);
        ay += v0 * __uint_as_float(g0 & 0xFFFF0000u) + v1 * __uint_as_float(g1 & 0xFFFF0000u)
            + v2 * __uint_as_float(g2 & 0xFFFF0000u) + v3 * __uint_as_float(g3 & 0xFFFF0000u);
    }
    for (; e < end; e++) {
        int2 c = csr[e];
        unsigned g = hb[c.x * 64 + lane];
        float v = __int_as_float(c.y);
        ax += v * __uint_as_float(g << 16);
        ay += v * __uint_as_float(g & 0xFFFF0000u);
    }
    *((float2*)(neigh + (size_t)wave * H) + lane) = make_float2(ax, ay);
}

// fp32-gather variant (fallback when ws too small for hb)
__global__ __launch_bounds__(TPB) void k_spmm_csr_f32(
    const int* __restrict__ row_ptr, const int2* __restrict__ csr,
    const float* __restrict__ h, float* __restrict__ neigh)
{
    int wave = (int)((blockIdx.x * TPB + threadIdx.x) >> 6);
    if (wave >= N_NODES) return;
    int lane = threadIdx.x & 63;
    int start = row_ptr[wave];
    int end   = row_ptr[wave + 1];
    float ax = 0.f, ay = 0.f;
    int e = start;
    for (; e + 2 <= end; e += 2) {
        int2 cv0 = csr[e];
        int2 cv1 = csr[e + 1];
        const float2 h0 = *((const float2*)(h + (size_t)cv0.x * H) + lane);
        const float2 h1 = *((const float2*)(h + (size_t)cv1.x * H) + lane);
        float v0 = __int_as_float(cv0.y);
        float v1 = __int_as_float(cv1.y);
        ax += v0 * h0.x + v1 * h1.x;
        ay += v0 * h0.y + v1 * h1.y;
    }
    if (e < end) {
        int2 cv = csr[e];
        const float2 hv = *((const float2*)(h + (size_t)cv.x * H) + lane);
        float v = __int_as_float(cv.y);
        ax += v * hv.x;
        ay += v * hv.y;
    }
    *((float2*)(neigh + (size_t)wave * H) + lane) = make_float2(ax, ay);
}

// K2 (fallback): atomic SpMM if ws too small for any CSR
__global__ __launch_bounds__(TPB) void k_spmm_atomic(
    const int* __restrict__ erow, const int* __restrict__ ecol,
    const float* __restrict__ eval, const float* __restrict__ h,
    float* __restrict__ neigh)
{
    unsigned int gid = blockIdx.x * TPB + threadIdx.x;
    int e = (int)(gid >> 5);
    if (e >= N_EDGES) return;
    int c = ((int)gid & 31) * 4;
    int col = ecol[e];
    int row = erow[e];
    float v = eval[e];
    const float4 hv = *(const float4*)(h + (size_t)col * H + c);
    float* dst = neigh + (size_t)row * H + c;
    unsafeAtomicAdd(dst + 0, v * hv.x);
    unsafeAtomicAdd(dst + 1, v * hv.y);
    unsafeAtomicAdd(dst + 2, v * hv.z);
    unsafeAtomicAdd(dst + 3, v * hv.w);
}

// ---------------------------------------------------------------------------
// K3: dense layer update: h += relu(h@Ws + bs + neigh@Wn + bn)  (in place)
// 4x4 register blocking, float4 LDS reads, optional fused bf16 pack.
// ---------------------------------------------------------------------------
__global__ __launch_bounds__(TPB) void k_layer_dense(
    const float* __restrict__ neigh,
    const float* __restrict__ Wself, const float* __restrict__ bself,
    const float* __restrict__ Wneigh, const float* __restrict__ bneigh,
    float* __restrict__ h, unsigned* __restrict__ hb)
{
    __shared__ float h_lds[NPB][H];
    __shared__ float n_lds[NPB][H];
    const int tid  = threadIdx.x;
    const int base = blockIdx.x * NPB;

    for (int idx = tid; idx < NPB * H / 4; idx += TPB) {
        int r = idx >> 5, c = (idx & 31) * 4;
        *(float4*)&h_lds[r][c] = *(const float4*)(h + (size_t)(base + r) * H + c);
        *(float4*)&n_lds[r][c] = *(const float4*)(neigh + (size_t)(base + r) * H + c);
    }
    __syncthreads();

    const int c0 = (tid & 31) * 4;
    const int r0 = (tid >> 5) * 4;

    float acc[4][4];
    #pragma unroll
    for (int i = 0; i < 4; i++)
        #pragma unroll
        for (int j = 0; j < 4; j++) acc[i][j] = 0.f;

    for (int k = 0; k < H; k += 4) {
        float4 a[4], b[4];
        #pragma unroll
        for (int i = 0; i < 4; i++) {
            a[i] = *(const float4*)&h_lds[r0 + i][k];
            b[i] = *(const float4*)&n_lds[r0 + i][k];
        }
        #pragma unroll
        for (int kk = 0; kk < 4; kk++) {
            float4 ws = *(const float4*)(Wself  + (size_t)(k + kk) * H + c0);
            float4 wn = *(const float4*)(Wneigh + (size_t)(k + kk) * H + c0);
            const float* wsf = (const float*)&ws;
            const float* wnf = (const float*)&wn;
            #pragma unroll
            for (int i = 0; i < 4; i++) {
                float av = ((const float*)&a[i])[kk];
                float bv = ((const float*)&b[i])[kk];
                #pragma unroll
                for (int j = 0; j < 4; j++)
                    acc[i][j] += av * wsf[j] + bv * wnf[j];
            }
        }
    }

    float4 bs = *(const float4*)(bself + c0);
    float4 bn = *(const float4*)(bneigh + c0);
    const float* bsf = (const float*)&bs;
    const float* bnf = (const float*)&bn;
    #pragma unroll
    for (int i = 0; i < 4; i++) {
        int node = base + r0 + i;
        float4 out;
        float* of = (float*)&out;
        #pragma unroll
        for (int j = 0; j < 4; j++) {
            float v = fmaxf(acc[i][j] + bsf[j] + bnf[j], 0.f);
            of[j] = h_lds[r0 + i][c0 + j] + v;
        }
        *(float4*)(h + (size_t)node * H + c0) = out;
        if (hb) {
            uint2 p;
            p.x = bf_rne(of[0]) | (bf_rne(of[1]) << 16);
            p.y = bf_rne(of[2]) | (bf_rne(of[3]) << 16);
            *(uint2*)(hb + (size_t)node * 64 + (c0 >> 1)) = p;
        }
    }
}

// ---------------------------------------------------------------------------
// K4: mean/max pool (h >= 0 so int atomicMax and zero identity are valid)
// ---------------------------------------------------------------------------
__global__ __launch_bounds__(TPB) void k_reduce(
    const float* __restrict__ h, float* __restrict__ g)
{
    __shared__ float s_sum[TPB];
    __shared__ float s_max[TPB];
    const int tid = threadIdx.x;
    const int col = tid & 127;
    const int rg  = tid >> 7;

    float sum = 0.f, mx = 0.f;
    for (int row = blockIdx.x * 2 + rg; row < N_NODES; row += gridDim.x * 2) {
        float v = h[(size_t)row * H + col];
        sum += v;
        mx = fmaxf(mx, v);
    }
    s_sum[tid] = sum;
    s_max[tid] = mx;
    __syncthreads();
    if (tid < 128) {
        sum = s_sum[tid] + s_sum[tid + 128];
        mx  = fmaxf(s_max[tid], s_max[tid + 128]);
        unsafeAtomicAdd(&g[col], sum);
        atomicMax((int*)&g[128 + col], __float_as_int(mx));
    }
}

__global__ void k_finalize(float* __restrict__ g)
{
    int t = threadIdx.x;
    if (t < 128) g[t] *= (1.0f / (float)N_NODES);
}

// ---------------------------------------------------------------------------
extern "C" void kernel_launch(void* const* d_in, const int* in_sizes, int n_in,
                              void* d_out, int out_size, void* d_ws, size_t ws_size,
                              hipStream_t stream)
{
    const int*   midx  = (const int*)  d_in[0];
    const int*   widx  = (const int*)  d_in[1];
    const int*   tidx  = (const int*)  d_in[2];
    const float* cont  = (const float*)d_in[3];
    const int*   erow  = (const int*)  d_in[4];
    const int*   ecol  = (const int*)  d_in[5];
    const float* eval  = (const float*)d_in[6];
    const float* memb  = (const float*)d_in[7];
    const float* wemb  = (const float*)d_in[8];
    const float* temb  = (const float*)d_in[9];
    const float* W1    = (const float*)d_in[10];
    const float* b1    = (const float*)d_in[11];
    const float* W2    = (const float*)d_in[12];
    const float* b2    = (const float*)d_in[13];
    const float* Wself = (const float*)d_in[14];
    const float* bself = (const float*)d_in[15];
    const float* Wneigh= (const float*)d_in[16];
    const float* bneigh= (const float*)d_in[17];

    float* g = (float*)d_out;   // [256]
    float* h = g + 256;         // [N, H] lives in d_out

    // ---- workspace layout ----
    float*    neigh      = (float*)d_ws;                             // 102.4 MB
    unsigned* hb         = (unsigned*)(neigh + (size_t)N_NODES * H); // 51.2 MB
    int*      row_ptr    = (int*)(hb + (size_t)N_NODES * H / 2);
    int*      row_cnt    = row_ptr + (N_NODES + 2);
    int*      row_work   = row_cnt + N_NODES;
    int*      block_sums = row_work + N_NODES;
    long long* csr       = (long long*)(block_sums + 1024);          // 51.2 MB

    const size_t base_bytes = (size_t)N_NODES * H * 4
                            + (size_t)(3 * N_NODES + 2 + 1024) * 4
                            + (size_t)N_EDGES * 8;
    const size_t ws_full    = base_bytes + (size_t)N_NODES * H * 2;  // ~207 MB
    const bool use_csr  = (ws_size >= base_bytes);
    const bool use_bf16 = (ws_size >= ws_full);

    if (use_csr && !use_bf16) {
        // compact layout without hb
        row_ptr    = (int*)(neigh + (size_t)N_NODES * H);
        row_cnt    = row_ptr + (N_NODES + 2);
        row_work   = row_cnt + N_NODES;
        block_sums = row_work + N_NODES;
        csr        = (long long*)(block_sums + 1024);
    }

    hipMemsetAsync(d_out, 0, 256 * sizeof(float), stream);

    k_input_mlp<<<N_NODES / NPB, TPB, 0, stream>>>(
        midx, widx, tidx, cont, memb, wemb, temb, W1, b1, W2, b2, h,
        use_bf16 ? hb : nullptr);

    if (use_csr) {
        hipMemsetAsync(row_cnt, 0, N_NODES * sizeof(int), stream);
        k_histogram<<<(N_EDGES + TPB - 1) / TPB, TPB, 0, stream>>>(erow, row_cnt);
        k_scan_block_sums<<<N_SCAN_BLOCKS, SCAN_CHUNK, 0, stream>>>(row_cnt, block_sums);
        k_scan_tops<<<1, 1024, 0, stream>>>(block_sums, row_ptr);
        k_scan_final<<<N_SCAN_BLOCKS, SCAN_CHUNK, 0, stream>>>(
            row_cnt, block_sums, row_ptr, row_work);
        k_scatter<<<(N_EDGES + TPB - 1) / TPB, TPB, 0, stream>>>(
            erow, ecol, eval, row_work, csr);

        for (int l = 0; l < 2; l++) {
            if (use_bf16) {
                k_spmm_csr_bf16<<<(N_NODES * 64) / TPB, TPB, 0, stream>>>(
                    row_ptr, (const int2*)csr, hb, neigh);
            } else {
                k_spmm_csr_f32<<<(N_NODES * 64) / TPB, TPB, 0, stream>>>(
                    row_ptr, (const int2*)csr, h, neigh);
            }
            // pack hb only when another SpMM will consume it (l == 0)
            k_layer_dense<<<N_NODES / NPB, TPB, 0, stream>>>(
                neigh, Wself + (size_t)l * H * H, bself + (size_t)l * H,
                Wneigh + (size_t)l * H * H, bneigh + (size_t)l * H, h,
                (use_bf16 && l == 0) ? hb : nullptr);
        }
    } else {
        for (int l = 0; l < 2; l++) {
            hipMemsetAsync(neigh, 0, (size_t)N_NODES * H * sizeof(float), stream);
            unsigned int nthreads = (unsigned int)N_EDGES * 32u;
            k_spmm_atomic<<<nthreads / TPB, TPB, 0, stream>>>(erow, ecol, eval, h, neigh);
            k_layer_dense<<<N_NODES / NPB, TPB, 0, stream>>>(
                neigh, Wself + (size_t)l * H * H, bself + (size_t)l * H,
                Wneigh + (size_t)l * H * H, bneigh + (size_t)l * H, h, nullptr);
        }
    }

    k_reduce<<<2048, TPB, 0, stream>>>(h, g);
    k_finalize<<<1, 128, 0, stream>>>(g);
}